// Round 11
// baseline (461.946 us; speedup 1.0000x reference)
//
#include <hip/hip_runtime.h>

#define F_N   150000
#define K_N   5
#define S_N   32
#define V_N   100000
#define NITER 5
#define MLP_N 330
#define SHIFTV (-500.0f)
#define W_ELL 32                         // max degree (Poisson mean 7.5; P(deg>32) ~ 1e-11/var)
#define DEG_PAD 16                       // one deg counter per 64B line

#define FBLK  ((F_N + 255) / 256)        // 587
#define F2BLK ((2*F_N + 255) / 256)      // 1172 (2 threads/factor)
#define GBLK  ((V_N * 8 + 255) / 256)    // 3125 (8 threads/variable)
#define EBLK  ((F_N * K_N + 255) / 256)  // 2930
#define BBLK  (6 * FBLK)                 // 3522 (5/6 fill, 1/6 init)

__device__ __forceinline__ float lse2(float a, float b) {
    float mx = fmaxf(a, b);
    return mx + __logf(__expf(a - mx) + __expf(b - mx));
}

// ---- block-specialized: edge-slot assignment || m_1 init -------------------
__global__ __launch_bounds__(256) void k_build(
    const float* __restrict__ prv_fb,   // [F][32]
    const float* __restrict__ prv_v2f,  // [F][5][2]
    const int*   __restrict__ vidx,     // [F][5]
    float2*      __restrict__ m_out,    // [5][F]
    int*         __restrict__ deg,      // [V*DEG_PAD] (zeroed)
    int*         __restrict__ ellpos)   // [F*K] edge -> mell slot
{
    int g = blockIdx.x / 6, r = blockIdx.x % 6;

    if (r < 5) {
        int e = (g * 5 + r) * 256 + threadIdx.x;
        if (e >= F_N * K_N) return;
        int v = vidx[e];
        int pos = atomicAdd(&deg[v * DEG_PAD], 1);
        ellpos[e] = (pos < W_ELL) ? v * W_ELL + pos : V_N * W_ELL;  // overflow -> dump
        return;
    }

    int f = g * 256 + threadIdx.x;
    if (f >= F_N) return;

    float fb[S_N];
    const float4* p4 = reinterpret_cast<const float4*>(prv_fb + (size_t)f * S_N);
    #pragma unroll
    for (int i = 0; i < S_N / 4; ++i) {
        float4 v = p4[i];
        fb[i*4+0] = v.x; fb[i*4+1] = v.y; fb[i*4+2] = v.z; fb[i*4+3] = v.w;
    }
    float M = fb[0];
    #pragma unroll
    for (int s = 1; s < S_N; ++s) M = fmaxf(M, fb[s]);
    float T = 0.0f;
    float S0[K_N] = {0.f, 0.f, 0.f, 0.f, 0.f};
    #pragma unroll
    for (int s = 0; s < S_N; ++s) {
        float t = __expf(fb[s] - M);
        T += t;
        #pragma unroll
        for (int k = 0; k < K_N; ++k)
            if (((s >> k) & 1) == 0) S0[k] += t;
    }
    #pragma unroll
    for (int k = 0; k < K_N; ++k) {
        float v0 = prv_v2f[(size_t)f * (K_N*2) + k*2 + 0];
        float v1 = prv_v2f[(size_t)f * (K_N*2) + k*2 + 1];
        float u0 = __logf(S0[k])     - v0;
        float u1 = __logf(T - S0[k]) - v1;
        float l  = lse2(u0, u1);
        m_out[k*F_N + f] = make_float2(u0 - l, u1 - l);
    }
}

// ---- seed mell from m_1; compact deg copy ----------------------------------
__global__ __launch_bounds__(256) void k_scatter0(
    const int*    __restrict__ ellpos,   // [F*K]
    const float2* __restrict__ m,        // [5][F]
    const int*    __restrict__ deg,      // [V*DEG_PAD]
    float2*       __restrict__ mell,     // [V*W_ELL + 1]
    int*          __restrict__ degc)     // [V]
{
    int e = blockIdx.x * 256 + threadIdx.x;
    if (e < V_N) degc[e] = deg[e * DEG_PAD];
    if (e >= F_N * K_N) return;
    int f = e / K_N;
    int k = e - f * K_N;
    mell[ellpos[e]] = m[k * F_N + f];
}

// ---- gather: vb[v] = sum of mell row v (contiguous); var_term partials -----
__global__ __launch_bounds__(256) void k_gather(
    const float2* __restrict__ mell,     // [V][W_ELL]
    const int*    __restrict__ degc,     // [V]
    float2*       __restrict__ vb,       // [V] raw
    float2*       __restrict__ cpart,    // [NITER][GBLK]
    int iter)
{
    __shared__ float2 wred[4];
    int t = blockIdx.x * 256 + threadIdx.x;
    int v = t >> 3, sub = t & 7;
    int lane = threadIdx.x & 63;

    float a0 = 0.0f, a1 = 0.0f;
    int n = 0;
    if (v < V_N) {
        n = degc[v];
        int nn = n < W_ELL ? n : W_ELL;
        const float2* row = mell + (size_t)v * W_ELL;
        for (int i = sub; i < nn; i += 8) {
            float2 mm = row[i];
            a0 += mm.x; a1 += mm.y;
        }
    }
    a0 += __shfl_xor(a0, 1); a1 += __shfl_xor(a1, 1);
    a0 += __shfl_xor(a0, 2); a1 += __shfl_xor(a1, 2);
    a0 += __shfl_xor(a0, 4); a1 += __shfl_xor(a1, 4);

    float c0 = 0.0f, c1 = 0.0f;
    if (v < V_N && sub == 0) {
        vb[v] = make_float2(a0, a1);
        float l = lse2(a0, a1);
        float b0 = a0 - l, b1 = a1 - l;
        float dm1 = (float)n - 1.0f;
        c0 = dm1 * __expf(b0) * b0;
        c1 = dm1 * __expf(b1) * b1;
    }
    #pragma unroll
    for (int mk = 32; mk >= 1; mk >>= 1) {
        c0 += __shfl_xor(c0, mk);
        c1 += __shfl_xor(c1, mk);
    }
    if (lane == 0) wred[threadIdx.x >> 6] = make_float2(c0, c1);
    __syncthreads();
    if (threadIdx.x == 0) {
        float2 s = wred[0];
        s.x += wred[1].x + wred[2].x + wred[3].x;
        s.y += wred[1].y + wred[2].y + wred[3].y;
        cpart[iter * GBLK + blockIdx.x] = s;
    }
}

// ---- factor iteration: 2 threads/factor (16 states each) -------------------
template <bool LAST>
__global__ __launch_bounds__(256) void k_iter(
    const float*  __restrict__ pot,      // [F][32]
    const int*    __restrict__ vidx,     // [F][5]
    const int*    __restrict__ ellpos,   // [F*K]
    float2*       __restrict__ m,        // [5][F], in-place update
    float2*       __restrict__ mell,     // [V][W_ELL]
    const float2* __restrict__ vb,       // [V] raw
    float*        __restrict__ fpart,    // [NITER][F2BLK][64]
    int iter)
{
    const int lane = threadIdx.x & 63;
    __shared__ float red[4][64];

    int t = blockIdx.x * 256 + threadIdx.x;
    int f = t >> 1, p = t & 1;
    bool valid = f < F_N;
    int fc = valid ? f : (F_N - 1);

    float2 mm[K_N];
    #pragma unroll
    for (int k = 0; k < K_N; ++k) mm[k] = m[k*F_N + fc];
    int vi[K_N];
    #pragma unroll
    for (int k = 0; k < K_N; ++k) vi[k] = vidx[(size_t)fc * K_N + k];

    float v2f[K_N][2];
    #pragma unroll
    for (int k = 0; k < K_N; ++k) {
        float2 b = vb[vi[k]];
        float a0 = b.x - mm[k].x;
        float a1 = b.y - mm[k].y;
        float l = lse2(a0, a1);
        v2f[k][0] = a0 - l;
        v2f[k][1] = a1 - l;
    }

    // my 16 states: s = 16p + j.  pot reads fully coalesced (64B per lane).
    float fb[16];
    const float4* p4 = reinterpret_cast<const float4*>(pot + (size_t)fc * S_N + p * 16);
    #pragma unroll
    for (int i = 0; i < 4; ++i) {
        float4 pv = p4[i];
        int s = p*16 + i*4;
        fb[i*4+0] = pv.x + v2f[0][(s+0)&1] + v2f[1][((s+0)>>1)&1] + v2f[2][((s+0)>>2)&1] + v2f[3][((s+0)>>3)&1] + v2f[4][((s+0)>>4)&1];
        fb[i*4+1] = pv.y + v2f[0][(s+1)&1] + v2f[1][((s+1)>>1)&1] + v2f[2][((s+1)>>2)&1] + v2f[3][((s+1)>>3)&1] + v2f[4][((s+1)>>4)&1];
        fb[i*4+2] = pv.z + v2f[0][(s+2)&1] + v2f[1][((s+2)>>1)&1] + v2f[2][((s+2)>>2)&1] + v2f[3][((s+2)>>3)&1] + v2f[4][((s+2)>>4)&1];
        fb[i*4+3] = pv.w + v2f[0][(s+3)&1] + v2f[1][((s+3)>>1)&1] + v2f[2][((s+3)>>2)&1] + v2f[3][((s+3)>>3)&1] + v2f[4][((s+3)>>4)&1];
    }

    float M = fb[0];
    #pragma unroll
    for (int j = 1; j < 16; ++j) M = fmaxf(M, fb[j]);
    M = fmaxf(M, __shfl_xor(M, 1));              // pair-combine max

    float T = 0.0f;
    float S0[K_N] = {0.f, 0.f, 0.f, 0.f, 0.f};
    #pragma unroll
    for (int j = 0; j < 16; ++j) {
        int s = p*16 + j;
        float e = __expf(fb[j] - M);
        T += e;
        #pragma unroll
        for (int k = 0; k < K_N; ++k)
            if (((s >> k) & 1) == 0) S0[k] += e;
    }
    T += __shfl_xor(T, 1);
    #pragma unroll
    for (int k = 0; k < K_N; ++k) S0[k] += __shfl_xor(S0[k], 1);

    if (!LAST) {
        // p=0 writes k=0,1,2; p=1 writes k=3,4
        #pragma unroll
        for (int k = 0; k < K_N; ++k) {
            bool mine = p ? (k >= 3) : (k < 3);
            if (valid && mine) {
                float u0 = __logf(S0[k])     - v2f[k][0];
                float u1 = __logf(T - S0[k]) - v2f[k][1];
                float l  = lse2(u0, u1);
                float2 nm = make_float2(u0 - l, u1 - l);
                m[k*F_N + f] = nm;
                mell[ellpos[(size_t)f * K_N + k]] = nm;
            }
        }
    }

    // features: arr[j] = j<16 ? energy(state 16p+j) : ent(state 16p+j-16)
    float invT = 1.0f / T;
    float logT = __logf(T);
    float arr[32];
    #pragma unroll
    for (int j = 0; j < 16; ++j) {
        int s = p*16 + j;
        float pe  = __expf(fb[j] - M) * invT;
        float fbn = fb[j] - M - logT;
        float w   = v2f[0][s&1] + v2f[1][(s>>1)&1] + v2f[2][(s>>2)&1]
                  + v2f[3][(s>>3)&1] + v2f[4][(s>>4)&1];
        arr[j]      = valid ? pe * (fb[j] - w) : 0.0f;
        arr[16 + j] = valid ? -pe * fbn        : 0.0f;
    }

    // 5-round halving over masks {2,4,8,16,32}; lengths 16,8,4,2,1.
    int len = 16;
    #pragma unroll
    for (int mk = 2; mk <= 32; mk <<= 1) {
        bool upper = (lane & mk) != 0;
        #pragma unroll
        for (int j = 0; j < 16; ++j) {     // j < len (len <= 16)
            if (j < len) {
                float send = upper ? arr[j] : arr[j + len];
                float recv = __shfl_xor(send, mk);
                float keep = upper ? arr[j + len] : arr[j];
                arr[j] = keep + recv;
            }
        }
        len >>= 1;
    }
    // lane -> feature: j_local from bits 1..5 of lane; global g.
    int jl = (((lane>>1)&1)<<4) | (((lane>>2)&1)<<3) | (((lane>>3)&1)<<2)
           | (((lane>>4)&1)<<1) | ((lane>>5)&1);
    int g  = (lane & 1) * 16 + jl + (jl < 16 ? 0 : 16);

    red[threadIdx.x >> 6][g] = arr[0];
    __syncthreads();
    if (threadIdx.x < 64) {
        float s = red[0][threadIdx.x] + red[1][threadIdx.x]
                + red[2][threadIdx.x] + red[3][threadIdx.x];
        fpart[((size_t)iter * F2BLK + blockIdx.x) * 64 + threadIdx.x] = s;
    }
}

// ---- parallel reduce fpart + cpart into x[330] -----------------------------
__global__ __launch_bounds__(256) void k_vt(
    const float*  __restrict__ fpart,    // [NITER][F2BLK][64]
    const float2* __restrict__ cpart,    // [NITER][GBLK]
    float*        __restrict__ x)        // [330]
{
    __shared__ float red[256];
    int b = blockIdx.x, t = threadIdx.x;
    float acc = 0.0f;
    if (b < 320) {
        int it = b >> 6, s = b & 63;
        for (int i = t; i < F2BLK; i += 256)
            acc += fpart[((size_t)it * F2BLK + i) * 64 + s];
    } else {
        int idx = b - 320;
        int it = idx >> 1, c = idx & 1;
        for (int i = t; i < GBLK; i += 256) {
            float2 p = cpart[it * GBLK + i];
            acc += c ? p.y : p.x;
        }
    }
    red[t] = acc;
    __syncthreads();
    #pragma unroll
    for (int off = 128; off >= 1; off >>= 1) {
        if (t < off) red[t] += red[t + off];
        __syncthreads();
    }
    if (t == 0) {
        if (b < 320) {
            int it = b >> 6, s = b & 63;
            x[it*66 + s] = red[0];
        } else {
            int idx = b - 320;
            int it = idx >> 1, c = idx & 1;
            x[it*66 + 64 + c] = red[0];
        }
    }
}

// ---- fused MLP (single block; wave-per-output layer 1) ---------------------
__global__ __launch_bounds__(256) void k_mlp(
    const float* __restrict__ x, const float* __restrict__ w1,
    const float* __restrict__ b1, const float* __restrict__ w2,
    const float* __restrict__ b2, float* __restrict__ out)
{
    __shared__ float xs[MLP_N];
    __shared__ float hs[MLP_N];
    __shared__ float red[256];
    int t = threadIdx.x, wid = t >> 6, lane = t & 63;

    for (int i = t; i < MLP_N; i += 256) xs[i] = x[i];
    __syncthreads();

    for (int j = wid; j < MLP_N; j += 4) {
        float s = 0.0f;
        for (int i = lane; i < MLP_N; i += 64) s += xs[i] * w1[(size_t)j * MLP_N + i];
        #pragma unroll
        for (int mk = 32; mk >= 1; mk >>= 1) s += __shfl_xor(s, mk);
        if (lane == 0) hs[j] = fmaxf(s + b1[j], SHIFTV);
    }
    __syncthreads();

    float s = 0.0f;
    for (int i = t; i < MLP_N; i += 256) s += hs[i] * w2[i];
    red[t] = s;
    __syncthreads();
    #pragma unroll
    for (int off = 128; off >= 1; off >>= 1) {
        if (t < off) red[t] += red[t + off];
        __syncthreads();
    }
    if (t == 0) out[0] = fmaxf(red[0] + b2[0], SHIFTV);
}

// ---- launch ------------------------------------------------------------------
extern "C" void kernel_launch(void* const* d_in, const int* in_sizes, int n_in,
                              void* d_out, int out_size, void* d_ws, size_t ws_size,
                              hipStream_t stream)
{
    (void)in_sizes; (void)n_in; (void)out_size; (void)ws_size;
    const float* pot  = (const float*)d_in[0];
    const int*   vidx = (const int*)  d_in[1];
    const float* pv2f = (const float*)d_in[2];
    // d_in[3] = prv_f2v (unused by the reference)
    const float* pfb  = (const float*)d_in[4];
    const float* w1   = (const float*)d_in[5];
    const float* b1   = (const float*)d_in[6];
    const float* w2   = (const float*)d_in[7];
    const float* b2   = (const float*)d_in[8];

    // workspace layout
    float2* m      = (float2*)d_ws;                       // 5*F float2
    float2* mell   = m + 5 * F_N;                         // V*W_ELL + 32
    float2* vb     = mell + (size_t)V_N * W_ELL + 32;     // V float2
    float2* cpart  = vb + V_N;                            // NITER*GBLK float2
    float*  fpart  = (float*)(cpart + NITER * GBLK);      // NITER*F2BLK*64
    float*  x      = fpart + (size_t)NITER * F2BLK * 64;  // 330
    int*    ellpos = (int*)(x + MLP_N);                   // F*K
    int*    degc   = ellpos + (size_t)F_N * K_N;          // V
    int*    deg    = degc + V_N;                          // V*DEG_PAD (zeroed)

    hipMemsetAsync(deg, 0, (size_t)V_N * DEG_PAD * sizeof(int), stream);

    k_build<<<BBLK, 256, 0, stream>>>(pfb, pv2f, vidx, m, deg, ellpos);
    k_scatter0<<<EBLK, 256, 0, stream>>>(ellpos, m, deg, mell, degc);

    for (int it = 0; it < NITER; ++it) {
        k_gather<<<GBLK, 256, 0, stream>>>(mell, degc, vb, cpart, it);
        if (it < NITER - 1)
            k_iter<false><<<F2BLK, 256, 0, stream>>>(pot, vidx, ellpos, m, mell, vb, fpart, it);
        else
            k_iter<true><<<F2BLK, 256, 0, stream>>>(pot, vidx, ellpos, m, mell, vb, fpart, it);
    }

    k_vt<<<330, 256, 0, stream>>>(fpart, cpart, x);
    k_mlp<<<1, 256, 0, stream>>>(x, w1, b1, w2, b2, (float*)d_out);
}

// Round 12
// 199.625 us; speedup vs baseline: 2.3141x; 2.3141x over previous
//
#include <hip/hip_runtime.h>

#define F_N   150000
#define K_N   5
#define S_N   32
#define V_N   100000
#define NITER 5
#define MLP_N 330
#define SHIFTV (-500.0f)
#define W_ELL 32                         // max degree (Poisson mean 7.5; P(deg>32) ~ 1e-11/var)

#define FBLK  ((F_N + 255) / 256)        // 587
#define GBLK  ((V_N * 8 + 255) / 256)    // 3125 (8 threads/variable)
#define EBLK  ((F_N * K_N + 255) / 256)  // 2930 (1 thread/edge)

__device__ __forceinline__ float lse2(float a, float b) {
    float mx = fmaxf(a, b);
    return mx + __logf(__expf(a - mx) + __expf(b - mx));
}

// ---- build: 1 thread/edge. atomic slot-claim issued FIRST; factor-f m_1
// math (5x redundant, pfb row L1-broadcast across the 5 lanes of f) hides
// under the atomic round-trip; then pos lands the mell seed. Replaces the
// old k_build + k_scatter0 pair.
__global__ __launch_bounds__(256) void k_build(
    const float* __restrict__ prv_fb,   // [F][32]
    const float* __restrict__ prv_v2f,  // [F][5][2]
    const int*   __restrict__ vidx,     // [F][5]
    float2*      __restrict__ m_out,    // [5][F]
    float2*      __restrict__ mell,     // [V*W_ELL + 1]
    int*         __restrict__ deg,      // [V] (zeroed)
    int*         __restrict__ ellpos)   // [F*K] edge -> mell slot
{
    int e = blockIdx.x * 256 + threadIdx.x;
    if (e >= F_N * K_N) return;
    int f = e / K_N;
    int k = e - f * K_N;
    int v = vidx[e];

    int pos = atomicAdd(&deg[v], 1);          // issue early; consumed last

    // ---- factor-f math (hides under atomic latency) ----
    float fb[S_N];
    const float4* p4 = reinterpret_cast<const float4*>(prv_fb + (size_t)f * S_N);
    #pragma unroll
    for (int i = 0; i < S_N / 4; ++i) {
        float4 q = p4[i];
        fb[i*4+0] = q.x; fb[i*4+1] = q.y; fb[i*4+2] = q.z; fb[i*4+3] = q.w;
    }
    float M = fb[0];
    #pragma unroll
    for (int s = 1; s < S_N; ++s) M = fmaxf(M, fb[s]);
    float T = 0.0f, S0 = 0.0f;
    #pragma unroll
    for (int s = 0; s < S_N; ++s) {
        float t = __expf(fb[s] - M);
        T += t;
        if (((s >> k) & 1) == 0) S0 += t;
    }
    float v0 = prv_v2f[(size_t)e * 2 + 0];
    float v1 = prv_v2f[(size_t)e * 2 + 1];
    float u0 = __logf(S0)     - v0;
    float u1 = __logf(T - S0) - v1;
    float l  = lse2(u0, u1);
    float2 nm = make_float2(u0 - l, u1 - l);

    m_out[k*F_N + f] = nm;                                   // coalesced-ish
    int slot = (pos < W_ELL) ? v * W_ELL + pos : V_N * W_ELL;
    ellpos[e] = slot;                                        // coalesced
    mell[slot] = nm;                                         // scatter (1 per edge)
}

// ---- gather: vb[v] = sum of mell row v (contiguous); var_term partials -----
__global__ __launch_bounds__(256) void k_gather(
    const float2* __restrict__ mell,     // [V][W_ELL]
    const int*    __restrict__ deg,      // [V]
    float2*       __restrict__ vb,       // [V] raw
    float2*       __restrict__ cpart,    // [NITER][GBLK]
    int iter)
{
    __shared__ float2 wred[4];
    int t = blockIdx.x * 256 + threadIdx.x;
    int v = t >> 3, sub = t & 7;
    int lane = threadIdx.x & 63;

    float a0 = 0.0f, a1 = 0.0f;
    int n = 0;
    if (v < V_N) {
        n = deg[v];
        int nn = n < W_ELL ? n : W_ELL;
        const float2* row = mell + (size_t)v * W_ELL;
        for (int i = sub; i < nn; i += 8) {
            float2 mm = row[i];
            a0 += mm.x; a1 += mm.y;
        }
    }
    a0 += __shfl_xor(a0, 1); a1 += __shfl_xor(a1, 1);
    a0 += __shfl_xor(a0, 2); a1 += __shfl_xor(a1, 2);
    a0 += __shfl_xor(a0, 4); a1 += __shfl_xor(a1, 4);

    float c0 = 0.0f, c1 = 0.0f;
    if (v < V_N && sub == 0) {
        vb[v] = make_float2(a0, a1);
        float l = lse2(a0, a1);
        float b0 = a0 - l, b1 = a1 - l;
        float dm1 = (float)n - 1.0f;
        c0 = dm1 * __expf(b0) * b0;
        c1 = dm1 * __expf(b1) * b1;
    }
    #pragma unroll
    for (int mk = 32; mk >= 1; mk >>= 1) {
        c0 += __shfl_xor(c0, mk);
        c1 += __shfl_xor(c1, mk);
    }
    if (lane == 0) wred[threadIdx.x >> 6] = make_float2(c0, c1);
    __syncthreads();
    if (threadIdx.x == 0) {
        float2 s = wred[0];
        s.x += wred[1].x + wred[2].x + wred[3].x;
        s.y += wred[1].y + wred[2].y + wred[3].y;
        cpart[iter * GBLK + blockIdx.x] = s;
    }
}

// ---- fused factor iteration: 1 thread/factor, zero atomics -----------------
template <bool LAST>
__global__ __launch_bounds__(256) void k_iter(
    const float*  __restrict__ pot,      // [F][32]
    const int*    __restrict__ vidx,     // [F][5]
    const int*    __restrict__ ellpos,   // [F*K]
    float2*       __restrict__ m,        // [5][F], in-place update
    float2*       __restrict__ mell,     // [V][W_ELL]
    const float2* __restrict__ vb,       // [V] raw
    float*        __restrict__ fpart,    // [NITER][FBLK][64]
    int iter)
{
    const int lane = threadIdx.x & 63;
    __shared__ float red[256];

    int f = blockIdx.x * 256 + threadIdx.x;
    bool valid = f < F_N;
    int fc = valid ? f : (F_N - 1);

    float2 mm[K_N];
    #pragma unroll
    for (int k = 0; k < K_N; ++k) mm[k] = m[k*F_N + fc];
    int vi[K_N];
    #pragma unroll
    for (int k = 0; k < K_N; ++k) vi[k] = vidx[(size_t)fc * K_N + k];

    float v2f[K_N][2];
    #pragma unroll
    for (int k = 0; k < K_N; ++k) {
        float2 b = vb[vi[k]];
        float a0 = b.x - mm[k].x;
        float a1 = b.y - mm[k].y;
        float l = lse2(a0, a1);
        v2f[k][0] = a0 - l;
        v2f[k][1] = a1 - l;
    }

    float fb[S_N];
    const float4* p4 = reinterpret_cast<const float4*>(pot + (size_t)fc * S_N);
    #pragma unroll
    for (int i = 0; i < S_N / 4; ++i) {
        float4 pv = p4[i];
        int s = i * 4;
        fb[s+0] = pv.x + v2f[0][(s+0)&1] + v2f[1][((s+0)>>1)&1] + v2f[2][((s+0)>>2)&1] + v2f[3][((s+0)>>3)&1] + v2f[4][((s+0)>>4)&1];
        fb[s+1] = pv.y + v2f[0][(s+1)&1] + v2f[1][((s+1)>>1)&1] + v2f[2][((s+1)>>2)&1] + v2f[3][((s+1)>>3)&1] + v2f[4][((s+1)>>4)&1];
        fb[s+2] = pv.z + v2f[0][(s+2)&1] + v2f[1][((s+2)>>1)&1] + v2f[2][((s+2)>>2)&1] + v2f[3][((s+2)>>3)&1] + v2f[4][((s+2)>>4)&1];
        fb[s+3] = pv.w + v2f[0][(s+3)&1] + v2f[1][((s+3)>>1)&1] + v2f[2][((s+3)>>2)&1] + v2f[3][((s+3)>>3)&1] + v2f[4][((s+3)>>4)&1];
    }

    float M = fb[0];
    #pragma unroll
    for (int s = 1; s < S_N; ++s) M = fmaxf(M, fb[s]);

    float T = 0.0f;
    float S0[K_N] = {0.f, 0.f, 0.f, 0.f, 0.f};
    #pragma unroll
    for (int s = 0; s < S_N; ++s) {
        float t = __expf(fb[s] - M);
        T += t;
        #pragma unroll
        for (int k = 0; k < K_N; ++k)
            if (((s >> k) & 1) == 0) S0[k] += t;
    }

    if (!LAST) {
        int el[K_N];
        #pragma unroll
        for (int k = 0; k < K_N; ++k) el[k] = ellpos[(size_t)fc * K_N + k];
        #pragma unroll
        for (int k = 0; k < K_N; ++k) {
            float u0 = __logf(S0[k])     - v2f[k][0];
            float u1 = __logf(T - S0[k]) - v2f[k][1];
            float l  = lse2(u0, u1);
            if (valid) {
                float2 nm = make_float2(u0 - l, u1 - l);
                m[k*F_N + f] = nm;
                mell[el[k]]  = nm;
            }
        }
    }

    // features: energy[32] | fac_ent[32]
    float invT = 1.0f / T;
    float logT = __logf(T);
    float arr[2 * S_N];
    #pragma unroll
    for (int s = 0; s < S_N; ++s) {
        float p   = __expf(fb[s] - M) * invT;
        float fbn = fb[s] - M - logT;
        float w   = v2f[0][s&1] + v2f[1][(s>>1)&1] + v2f[2][(s>>2)&1]
                  + v2f[3][(s>>3)&1] + v2f[4][(s>>4)&1];
        float po  = fb[s] - w;
        arr[s]       = valid ? p * po   : 0.0f;
        arr[S_N + s] = valid ? -p * fbn : 0.0f;
    }

    #pragma unroll
    for (int mk = 32; mk >= 1; mk >>= 1) {
        bool upper = (lane & mk) != 0;
        #pragma unroll
        for (int j = 0; j < mk; ++j) {
            float send = upper ? arr[j] : arr[j + mk];
            float recv = __shfl_xor(send, mk);
            float keep = upper ? arr[j + mk] : arr[j];
            arr[j] = keep + recv;
        }
    }

    red[threadIdx.x] = arr[0];
    __syncthreads();
    if (threadIdx.x < 64) {
        float s = red[threadIdx.x] + red[64 + threadIdx.x]
                + red[128 + threadIdx.x] + red[192 + threadIdx.x];
        fpart[((size_t)iter * FBLK + blockIdx.x) * 64 + threadIdx.x] = s;
    }
}

// ---- parallel reduce fpart + cpart into x[330] -----------------------------
__global__ __launch_bounds__(256) void k_vt(
    const float*  __restrict__ fpart,    // [NITER][FBLK][64]
    const float2* __restrict__ cpart,    // [NITER][GBLK]
    float*        __restrict__ x)        // [330]
{
    __shared__ float red[256];
    int b = blockIdx.x, t = threadIdx.x;
    float acc = 0.0f;
    if (b < 320) {
        int it = b >> 6, s = b & 63;
        for (int i = t; i < FBLK; i += 256)
            acc += fpart[((size_t)it * FBLK + i) * 64 + s];
    } else {
        int idx = b - 320;
        int it = idx >> 1, c = idx & 1;
        for (int i = t; i < GBLK; i += 256) {
            float2 p = cpart[it * GBLK + i];
            acc += c ? p.y : p.x;
        }
    }
    red[t] = acc;
    __syncthreads();
    #pragma unroll
    for (int off = 128; off >= 1; off >>= 1) {
        if (t < off) red[t] += red[t + off];
        __syncthreads();
    }
    if (t == 0) {
        if (b < 320) {
            int it = b >> 6, s = b & 63;
            x[it*66 + s] = red[0];
        } else {
            int idx = b - 320;
            int it = idx >> 1, c = idx & 1;
            x[it*66 + 64 + c] = red[0];
        }
    }
}

// ---- MLP (split: 330 blocks then 1 block — never one-block a big stream) ---
__global__ __launch_bounds__(64) void k_mlp1(
    const float* __restrict__ x, const float* __restrict__ w1,
    const float* __restrict__ b1, float* __restrict__ h)
{
    int j = blockIdx.x;
    int lane = threadIdx.x;
    float s = 0.0f;
    for (int i = lane; i < MLP_N; i += 64) s += x[i] * w1[(size_t)j * MLP_N + i];
    #pragma unroll
    for (int mk = 32; mk >= 1; mk >>= 1) s += __shfl_xor(s, mk);
    if (lane == 0) h[j] = fmaxf(s + b1[j], SHIFTV);
}

__global__ __launch_bounds__(64) void k_mlp2(
    const float* __restrict__ h, const float* __restrict__ w2,
    const float* __restrict__ b2, float* __restrict__ out)
{
    int lane = threadIdx.x;
    float s = 0.0f;
    for (int i = lane; i < MLP_N; i += 64) s += h[i] * w2[i];
    #pragma unroll
    for (int mk = 32; mk >= 1; mk >>= 1) s += __shfl_xor(s, mk);
    if (lane == 0) out[0] = fmaxf(s + b2[0], SHIFTV);
}

// ---- launch ------------------------------------------------------------------
extern "C" void kernel_launch(void* const* d_in, const int* in_sizes, int n_in,
                              void* d_out, int out_size, void* d_ws, size_t ws_size,
                              hipStream_t stream)
{
    (void)in_sizes; (void)n_in; (void)out_size; (void)ws_size;
    const float* pot  = (const float*)d_in[0];
    const int*   vidx = (const int*)  d_in[1];
    const float* pv2f = (const float*)d_in[2];
    // d_in[3] = prv_f2v (unused by the reference)
    const float* pfb  = (const float*)d_in[4];
    const float* w1   = (const float*)d_in[5];
    const float* b1   = (const float*)d_in[6];
    const float* w2   = (const float*)d_in[7];
    const float* b2   = (const float*)d_in[8];

    // workspace layout
    float2* m      = (float2*)d_ws;                       // 5*F float2
    float2* mell   = m + 5 * F_N;                         // V*W_ELL + 32
    float2* vb     = mell + (size_t)V_N * W_ELL + 32;     // V float2
    float2* cpart  = vb + V_N;                            // NITER*GBLK float2
    float*  fpart  = (float*)(cpart + NITER * GBLK);      // NITER*FBLK*64
    float*  x      = fpart + (size_t)NITER * FBLK * 64;   // 330
    float*  h      = x + MLP_N;                           // 330
    int*    ellpos = (int*)(h + MLP_N);                   // F*K
    int*    deg    = ellpos + (size_t)F_N * K_N;          // V (zeroed)

    hipMemsetAsync(deg, 0, (size_t)V_N * sizeof(int), stream);

    k_build<<<EBLK, 256, 0, stream>>>(pfb, pv2f, vidx, m, mell, deg, ellpos);

    for (int it = 0; it < NITER; ++it) {
        k_gather<<<GBLK, 256, 0, stream>>>(mell, deg, vb, cpart, it);
        if (it < NITER - 1)
            k_iter<false><<<FBLK, 256, 0, stream>>>(pot, vidx, ellpos, m, mell, vb, fpart, it);
        else
            k_iter<true><<<FBLK, 256, 0, stream>>>(pot, vidx, ellpos, m, mell, vb, fpart, it);
    }

    k_vt<<<330, 256, 0, stream>>>(fpart, cpart, x);
    k_mlp1<<<MLP_N, 64, 0, stream>>>(x, w1, b1, h);
    k_mlp2<<<1, 64, 0, stream>>>(h, w2, b2, (float*)d_out);
}